// Round 4
// baseline (695.778 us; speedup 1.0000x reference)
//
#include <hip/hip_runtime.h>
#include <math.h>

// R5 (resubmit — R3 bench died on GPUAcquisitionTimeout, no measurement):
// bandwidth-discriminator — contiguous-per-instruction streaming.
//
// Evidence: R2/R3/R4 (structurally distinct: 3-dispatch+ws / zero-ws simple /
// 4x-ILP fast-path) all measure 680+-10 us. Fills (2.147 GiB, ~334 us) are
// unconditional; our kernel never appears in top-5 => kernel < 331 us.
// Two admissible models: (a) kernel ~=90 us + ~590 us harness floor;
// (b) kernel ~=300 us @ ~1.6 TB/s. This round attacks (b)'s only remaining
// mechanism with every streaming-BW lever at once:
//   - wave = 2 adjacent rows, 32 lanes/row: each global_load_dwordx4 is a
//     perfectly contiguous 1 KB wave transaction
//   - 8 independent preloaded float4 chains/thread (128 B in flight/thread)
//   - non-temporal emb loads + out stores (caches are flushed by the 2 GiB
//     poison fill every iteration anyway; keeps ptr/summary/dvec L2-resident)
// If dur_us stays ~680: model (a) confirmed by 4-way invariance -> roofline.

#define HDIM 128
#define NEPS 1e-12f
#define ROWS_PER_BLOCK 64   // 256 threads = 4 waves; 2 rows/wave-iter x 8 iters

typedef float f4v __attribute__((ext_vector_type(4)));

__global__ __launch_bounds__(256) void sim_fused(
    const float* __restrict__ emb,
    const float* __restrict__ summary,
    const int*   __restrict__ ptr,
    const float* __restrict__ dvec,
    const float* __restrict__ scale,
    float* __restrict__ out, int N, int B)
{
    __shared__ int s_bounds[2];

    const long long row0 = (long long)blockIdx.x * ROWS_PER_BLOCK;

    // threads 0/1: binary-search segment of first/last row of this block.
    // seg(i) = count of ptr[1..B] <= i  (searchsorted(ptr[1:], i, 'right')).
    if (threadIdx.x < 2) {
        long long r = row0 + (threadIdx.x ? ROWS_PER_BLOCK - 1 : 0);
        if (r > (long long)N - 1) r = (long long)N - 1;
        int lo = 0, hi = B;
        while (lo < hi) {
            int mid = (lo + hi) >> 1;
            if (ptr[1 + mid] <= (int)r) lo = mid + 1; else hi = mid;
        }
        s_bounds[threadIdx.x] = lo;
    }
    __syncthreads();
    const int s0 = s_bounds[0];
    const int s1 = s_bounds[1];

    const int wave = threadIdx.x >> 6;   // 0..3
    const int lane = threadIdx.x & 63;
    const int half = lane >> 5;          // row parity within the wave's pair
    const int l    = lane & 31;          // float4 index within the row
    const float sc = scale[0];

    // this thread's 8 rows: row0 + 8*it + 2*wave + half (it = 0..7), ascending
    const long long rbase = row0 + 2 * wave + half;

    // ---- preload all 8 emb float4s: 8 independent non-temporal chains ----
    f4v e[8];
    #pragma unroll
    for (int it = 0; it < 8; ++it) {
        const long long row = rbase + 8 * it;
        const f4v* p = (const f4v*)(emb + row * (long long)HDIM) + l;
        e[it] = (row < N) ? __builtin_nontemporal_load(p) : (f4v)(0.f);
    }

    const f4v dd = ((const f4v*)dvec)[l];

    if (s0 == s1) {
        // ---- fast path: whole block in one segment ----
        const f4v w  = ((const f4v*)(summary + (long long)s0 * HDIM))[l];
        const f4v wd = w * dd;
        #pragma unroll
        for (int it = 0; it < 8; ++it) {
            const long long row = rbase + 8 * it;
            if (row >= N) continue;
            float sumsq = 0.f, dot = 0.f;
            #pragma unroll
            for (int c = 0; c < 4; ++c) {
                sumsq = fmaf(e[it][c], e[it][c], sumsq);
                dot   = fmaf(e[it][c], wd[c],   dot);
            }
            #pragma unroll
            for (int m = 16; m >= 1; m >>= 1) {   // stays within 32-lane half
                sumsq += __shfl_xor(sumsq, m, 64);
                dot   += __shfl_xor(dot,   m, 64);
            }
            if (l == 0)
                __builtin_nontemporal_store(
                    dot / fmaxf(sqrtf(sumsq), NEPS) * sc, out + row);
        }
    } else {
        // ---- slow path: block spans >=1 boundary; rows ascend, s monotone ----
        int s = s0;
        #pragma unroll
        for (int it = 0; it < 8; ++it) {
            const long long row = rbase + 8 * it;
            if (row >= N) continue;
            while (s < s1 && ptr[s + 1] <= (int)row) ++s;
            const f4v w  = ((const f4v*)(summary + (long long)s * HDIM))[l];
            const f4v wd = w * dd;
            float sumsq = 0.f, dot = 0.f;
            #pragma unroll
            for (int c = 0; c < 4; ++c) {
                sumsq = fmaf(e[it][c], e[it][c], sumsq);
                dot   = fmaf(e[it][c], wd[c],   dot);
            }
            #pragma unroll
            for (int m = 16; m >= 1; m >>= 1) {
                sumsq += __shfl_xor(sumsq, m, 64);
                dot   += __shfl_xor(dot,   m, 64);
            }
            if (l == 0)
                __builtin_nontemporal_store(
                    dot / fmaxf(sqrtf(sumsq), NEPS) * sc, out + row);
        }
    }
}

extern "C" void kernel_launch(void* const* d_in, const int* in_sizes, int n_in,
                              void* d_out, int out_size, void* d_ws, size_t ws_size,
                              hipStream_t stream) {
    const float* emb     = (const float*)d_in[0];
    const float* summary = (const float*)d_in[1];
    const int*   ptr     = (const int*)d_in[2];
    const float* dvec    = (const float*)d_in[3];
    const float* scale   = (const float*)d_in[4];
    float*       out     = (float*)d_out;

    const int Hn = in_sizes[3];           // 128
    const int N  = in_sizes[0] / Hn;      // 1048576
    const int B  = in_sizes[1] / Hn;      // 1024

    (void)d_ws; (void)ws_size; (void)n_in; (void)out_size;

    sim_fused<<<(N + ROWS_PER_BLOCK - 1) / ROWS_PER_BLOCK, 256, 0, stream>>>(
        emb, summary, ptr, dvec, scale, out, N, B);
}